// Round 1
// 120.891 us; speedup vs baseline: 1.0154x; 1.0154x over previous
//
#include <hip/hip_runtime.h>
#include <math.h>

#define HH 496
#define WW 496
#define HWSZ (HH*WW)
#define NW 31
#define NWIN (NW*NW)   // 961

typedef float nf4 __attribute__((ext_vector_type(4)));  // native vec for nontemporal builtin

__constant__ float c_thetas[8] = {
    0.39269908169872414f, 0.7853981633974483f, 1.1780972450961724f,
    1.5707963267948966f,  1.9634954084936207f, 2.356194490192345f,
    2.748893571891069f,   3.141592653589793f};

// ---- Kernel 1: Gabor bank TRANSPOSED as filt[k][f] (k=0..24, f=c*8+t) + zero meanacc ----
__global__ void bank_kernel(const float* __restrict__ sigmas,
                            const float* __restrict__ lambdas,
                            float* __restrict__ filt,
                            float* __restrict__ meanacc) {
    int idx = threadIdx.x + blockIdx.x * blockDim.x;
    if (idx >= 1800) {
        if (idx < 1809) meanacc[(idx - 1800) * 16] = 0.0f;  // one per 64B line
        return;
    }
    int f = idx / 25, k = idx % 25;
    int dy = k / 5, dx = k % 5;
    int s = f / 24, rem = f % 24, l = rem / 8, t = rem % 8;
    float sig = sigmas[s], lam = lambdas[l], th = c_thetas[t];
    float y = (float)dy - 2.0f, x = (float)dx - 2.0f;
    float st = sinf(th), ct = cosf(th);
    float yt = -x * st + y * ct;
    float xt =  x * ct + y * st;
    float sx2 = sig * sig;          // sigma_x = sig
    float sy2 = 4.0f * sig * sig;   // sigma_y = sig/0.5
    float g = expf(-0.5f * (xt * xt / sx2 + yt * yt / sy2)) *
              cosf(6.28318530717958647692f * xt / lam + 1.5707963267948966f);
    filt[k * 72 + f] = g;           // transposed layout
}

// named accumulators -- arrays get demoted to scratch (VGPR=28 evidence, R6)
#define FMAS(FP, P) \
    a0  = fmaf(P, (FP)[0],  a0);  a1  = fmaf(P, (FP)[1],  a1);  \
    a2  = fmaf(P, (FP)[2],  a2);  a3  = fmaf(P, (FP)[3],  a3);  \
    a4  = fmaf(P, (FP)[4],  a4);  a5  = fmaf(P, (FP)[5],  a5);  \
    a6  = fmaf(P, (FP)[6],  a6);  a7  = fmaf(P, (FP)[7],  a7);  \
    a8  = fmaf(P, (FP)[8],  a8);  a9  = fmaf(P, (FP)[9],  a9);  \
    a10 = fmaf(P, (FP)[10], a10); a11 = fmaf(P, (FP)[11], a11); \
    a12 = fmaf(P, (FP)[12], a12); a13 = fmaf(P, (FP)[13], a13); \
    a14 = fmaf(P, (FP)[14], a14); a15 = fmaf(P, (FP)[15], a15); \
    a16 = fmaf(P, (FP)[16], a16); a17 = fmaf(P, (FP)[17], a17); \
    a18 = fmaf(P, (FP)[18], a18); a19 = fmaf(P, (FP)[19], a19); \
    a20 = fmaf(P, (FP)[20], a20); a21 = fmaf(P, (FP)[21], a21); \
    a22 = fmaf(P, (FP)[22], a22); a23 = fmaf(P, (FP)[23], a23);

// pixels held in named registers p0..p24 (one ds_read each, reused by all 72 filters)
#define STEP(K) { const float* fp = fbase + (K)*72; FMAS(fp, p##K) }

#define ALLSTEPS \
    STEP(0)  STEP(1)  STEP(2)  STEP(3)  STEP(4)  \
    STEP(5)  STEP(6)  STEP(7)  STEP(8)  STEP(9)  \
    STEP(10) STEP(11) STEP(12) STEP(13) STEP(14) \
    STEP(15) STEP(16) STEP(17) STEP(18) STEP(19) \
    STEP(20) STEP(21) STEP(22) STEP(23) STEP(24)

#define RED(CC, MV) { \
        float s = MV; \
        s += __shfl_down(s, 32, 64); s += __shfl_down(s, 16, 64); \
        s += __shfl_down(s,  8, 64); s += __shfl_down(s,  4, 64); \
        s += __shfl_down(s,  2, 64); s += __shfl_down(s,  1, 64); \
        if ((tid & 63) == 0) red[tid >> 6][CC] = s; }

// one channel group = 24 filters; accumulators live only inside this scope
#define CONVCG(CG) { \
        float a0=0,a1=0,a2=0,a3=0,a4=0,a5=0,a6=0,a7=0,a8=0,a9=0,a10=0,a11=0, \
              a12=0,a13=0,a14=0,a15=0,a16=0,a17=0,a18=0,a19=0,a20=0,a21=0,a22=0,a23=0; \
        const float* fbase = filt + (CG) * 24; \
        ALLSTEPS \
        float m0 = fmaxf(fmaxf(fmaxf(a0,a1),fmaxf(a2,a3)),fmaxf(fmaxf(a4,a5),fmaxf(a6,a7))); \
        float m1 = fmaxf(fmaxf(fmaxf(a8,a9),fmaxf(a10,a11)),fmaxf(fmaxf(a12,a13),fmaxf(a14,a15))); \
        float m2 = fmaxf(fmaxf(fmaxf(a16,a17),fmaxf(a18,a19)),fmaxf(fmaxf(a20,a21),fmaxf(a22,a23))); \
        out[((CG) * 3 + 0) * HWSZ + y * WW + x] = m0; \
        out[((CG) * 3 + 1) * HWSZ + y * WW + x] = m1; \
        out[((CG) * 3 + 2) * HWSZ + y * WW + x] = m2; \
        RED((CG) * 3 + 0, m0) RED((CG) * 3 + 1, m1) RED((CG) * 3 + 2, m2) \
    }

// ---- Kernel 2: conv, ALL 3 channel groups per block: tile staged once, 1800 FMA/thread ----
__global__ __launch_bounds__(256) void conv_kernel(
    const float* __restrict__ img, const float* __restrict__ filt,
    float* __restrict__ out, float* __restrict__ meanacc) {
    __shared__ float tile[20 * 20];
    __shared__ float red[4][9];
    int tid = threadIdx.x;
    int tx = tid & 15, ty = tid >> 4;
    int bx = blockIdx.x, by = blockIdx.y;

    for (int i = tid; i < 400; i += 256) {
        int tY = i / 20, tX = i % 20;
        int gy = by * 16 + tY - 2, gx = bx * 16 + tX - 2;
        float v = 0.0f;
        if (gy >= 0 && gy < HH && gx >= 0 && gx < WW) v = img[gy * WW + gx];
        tile[i] = v;
    }
    __syncthreads();

    int tbase = ty * 20 + tx;
    // hoist the 25 pixel loads into named registers (exactly 25 ds_read_b32, shared by all cgs)
    float p0  = tile[tbase +  0], p1  = tile[tbase +  1], p2  = tile[tbase +  2],
          p3  = tile[tbase +  3], p4  = tile[tbase +  4];
    float p5  = tile[tbase + 20], p6  = tile[tbase + 21], p7  = tile[tbase + 22],
          p8  = tile[tbase + 23], p9  = tile[tbase + 24];
    float p10 = tile[tbase + 40], p11 = tile[tbase + 41], p12 = tile[tbase + 42],
          p13 = tile[tbase + 43], p14 = tile[tbase + 44];
    float p15 = tile[tbase + 60], p16 = tile[tbase + 61], p17 = tile[tbase + 62],
          p18 = tile[tbase + 63], p19 = tile[tbase + 64];
    float p20 = tile[tbase + 80], p21 = tile[tbase + 81], p22 = tile[tbase + 82],
          p23 = tile[tbase + 83], p24 = tile[tbase + 84];

    int y = by * 16 + ty, x = bx * 16 + tx;

    CONVCG(0)
    CONVCG(1)
    CONVCG(2)

    __syncthreads();
    if (tid < 9)
        atomicAdd(&meanacc[tid * 16],
                  red[0][tid] + red[1][tid] + red[2][tid] + red[3][tid]);
}

// ---- Kernel 3: per-window validity FIRST, patch copy only for valid windows (~3.5%) ----
__global__ __launch_bounds__(256) void patch_kernel(
    const float* __restrict__ out, const float* __restrict__ meanacc,
    float* __restrict__ dst) {
    int w = blockIdx.x;
    int r = w / NW, cl = w % NW;
    int tid = threadIdx.x;
    __shared__ int lds_and[4];
    __shared__ int lds_or[4];

    // Stage 1: per-channel "argmax of thresholded window == 128" bit, AND over threads
    int wy = tid >> 4, wx = tid & 15;
    int rowbase = (r * 16 + wy) * WW + cl * 16 + wx;
    int cbase   = (r * 16 + 8) * WW + cl * 16;       // flat idx 128 = (8,0)
    int okmask = 0;
#pragma unroll
    for (int c = 0; c < 9; c++) {
        float m5 = meanacc[c * 16] * (5.0f / (float)HWSZ);
        float v  = out[c * HWSZ + rowbase];
        float vc = out[c * HWSZ + cbase];
        float thr  = (v  > m5) ? v  : 0.0f;
        float thrc = (vc > m5) ? vc : 0.0f;
        // first-occurrence argmax: earlier strictly less, later (incl. center) <=
        bool ok = (tid < 128) ? (thr < thrc) : (thr <= thrc);
        okmask |= (ok ? 1 : 0) << c;
    }
#pragma unroll
    for (int off = 1; off < 64; off <<= 1) okmask &= __shfl_xor(okmask, off, 64);
    if ((tid & 63) == 0) lds_and[tid >> 6] = okmask;
    __syncthreads();

    int am = lds_and[0] & lds_and[1] & lds_and[2] & lds_and[3];

    int i = tid >> 3;            // patch row 0..31
    int jg = (tid & 7) << 2;     // patch col group 0,4,...,28
    size_t dbase = (size_t)w * 1024 + i * 32 + jg;

    if (am == 0) {
        // no channel has center-argmax: entire 9-channel patch set is zero.
        // must still store (dst is poisoned), but skip all patch reads.
        nf4 z = (nf4){0.f, 0.f, 0.f, 0.f};
#pragma unroll
        for (int c = 0; c < 9; c++)
            __builtin_nontemporal_store(z, (nf4*)(dst + (size_t)c * NWIN * 1024 + dbase));
        return;
    }

    // Stage 2 (valid windows only, ~3.5%): one float4 per (thread, channel); nz bitmask
    int row = r * 16 + i - 8;
    int col = cl * 16 + jg - 8;
    // 4-aligned col groups never straddle the [0,496) edge (496 % 4 == 0)
    bool inb = (row >= 0 && row < HH && col >= 0 && col + 3 < WW);
    size_t pbase = (size_t)row * WW + col;
    int nzmask = 0;
    nf4 p0, p1, p2, p3, p4, p5, p6, p7, p8;
#define LOADP(C, V) { \
        V = (nf4){0.f, 0.f, 0.f, 0.f}; \
        if (inb) V = *(const nf4*)(out + (size_t)(C) * HWSZ + pbase); \
        if (V.x != 0.f || V.y != 0.f || V.z != 0.f || V.w != 0.f) nzmask |= 1 << (C); }
    LOADP(0,p0) LOADP(1,p1) LOADP(2,p2) LOADP(3,p3) LOADP(4,p4)
    LOADP(5,p5) LOADP(6,p6) LOADP(7,p7) LOADP(8,p8)

#pragma unroll
    for (int off = 1; off < 64; off <<= 1) nzmask |= __shfl_xor(nzmask, off, 64);
    if ((tid & 63) == 0) lds_or[tid >> 6] = nzmask;
    __syncthreads();

    int om = lds_or[0] | lds_or[1] | lds_or[2] | lds_or[3];

    // nontemporal: dst is streaming (35.4 MB, never re-read) -- keep `out` in L2
#define STOREP(C, V) { \
        float mk = ((om >> (C)) & 1) ? 1.0f : 0.0f; \
        V *= mk; \
        __builtin_nontemporal_store(V, (nf4*)(dst + (size_t)(C) * NWIN * 1024 + dbase)); }
    STOREP(0,p0) STOREP(1,p1) STOREP(2,p2) STOREP(3,p3) STOREP(4,p4)
    STOREP(5,p5) STOREP(6,p6) STOREP(7,p7) STOREP(8,p8)
}

extern "C" void kernel_launch(void* const* d_in, const int* in_sizes, int n_in,
                              void* d_out, int out_size, void* d_ws, size_t ws_size,
                              hipStream_t stream) {
    const float* img     = (const float*)d_in[0];
    const float* sigmas  = (const float*)d_in[1];
    const float* lambdas = (const float*)d_in[2];
    float* ws = (float*)d_ws;
    // ws layout (floats): filt[1800] @0, meanacc[144] @2048, out @4096
    float* filt    = ws;
    float* meanacc = ws + 2048;
    float* outb    = ws + 4096;   // 9*496*496 = 2,214,144 floats

    bank_kernel<<<8, 256, 0, stream>>>(sigmas, lambdas, filt, meanacc);
    conv_kernel<<<dim3(NW, NW), 256, 0, stream>>>(img, filt, outb, meanacc);
    patch_kernel<<<NWIN, 256, 0, stream>>>(outb, meanacc, (float*)d_out);
}

// Round 2
// 118.964 us; speedup vs baseline: 1.0318x; 1.0162x over previous
//
#include <hip/hip_runtime.h>
#include <math.h>

#define HH 496
#define WW 496
#define HWSZ (HH*WW)
#define NW 31
#define NWIN (NW*NW)   // 961
#define PARTSTRIDE 1024

typedef float nf4 __attribute__((ext_vector_type(4)));  // native vec for nontemporal builtin

__constant__ float c_thetas[8] = {
    0.39269908169872414f, 0.7853981633974483f, 1.1780972450961724f,
    1.5707963267948966f,  1.9634954084936207f, 2.356194490192345f,
    2.748893571891069f,   3.141592653589793f};

// named accumulators -- arrays get demoted to scratch (VGPR=28 evidence, prev session)
// filters read straight from LDS (flds), uniform address across the wave = broadcast,
// offsets are compile-time constants (byte offset = 96*(3K+CG), 16B-aligned for merging)
#define FMAS(B, P) \
    a0  = fmaf(P, flds[(B)+0],  a0);  a1  = fmaf(P, flds[(B)+1],  a1);  \
    a2  = fmaf(P, flds[(B)+2],  a2);  a3  = fmaf(P, flds[(B)+3],  a3);  \
    a4  = fmaf(P, flds[(B)+4],  a4);  a5  = fmaf(P, flds[(B)+5],  a5);  \
    a6  = fmaf(P, flds[(B)+6],  a6);  a7  = fmaf(P, flds[(B)+7],  a7);  \
    a8  = fmaf(P, flds[(B)+8],  a8);  a9  = fmaf(P, flds[(B)+9],  a9);  \
    a10 = fmaf(P, flds[(B)+10], a10); a11 = fmaf(P, flds[(B)+11], a11); \
    a12 = fmaf(P, flds[(B)+12], a12); a13 = fmaf(P, flds[(B)+13], a13); \
    a14 = fmaf(P, flds[(B)+14], a14); a15 = fmaf(P, flds[(B)+15], a15); \
    a16 = fmaf(P, flds[(B)+16], a16); a17 = fmaf(P, flds[(B)+17], a17); \
    a18 = fmaf(P, flds[(B)+18], a18); a19 = fmaf(P, flds[(B)+19], a19); \
    a20 = fmaf(P, flds[(B)+20], a20); a21 = fmaf(P, flds[(B)+21], a21); \
    a22 = fmaf(P, flds[(B)+22], a22); a23 = fmaf(P, flds[(B)+23], a23);

#define STEP(K, CG) { FMAS((K)*72 + (CG)*24, p##K) }

#define ALLSTEPS(CG) \
    STEP(0,CG)  STEP(1,CG)  STEP(2,CG)  STEP(3,CG)  STEP(4,CG)  \
    STEP(5,CG)  STEP(6,CG)  STEP(7,CG)  STEP(8,CG)  STEP(9,CG)  \
    STEP(10,CG) STEP(11,CG) STEP(12,CG) STEP(13,CG) STEP(14,CG) \
    STEP(15,CG) STEP(16,CG) STEP(17,CG) STEP(18,CG) STEP(19,CG) \
    STEP(20,CG) STEP(21,CG) STEP(22,CG) STEP(23,CG) STEP(24,CG)

#define RED(CC, MV) { \
        float s = MV; \
        s += __shfl_down(s, 32, 64); s += __shfl_down(s, 16, 64); \
        s += __shfl_down(s,  8, 64); s += __shfl_down(s,  4, 64); \
        s += __shfl_down(s,  2, 64); s += __shfl_down(s,  1, 64); \
        if ((tid & 63) == 0) red[tid >> 6][CC] = s; }

// one channel group = 24 filters; accumulators live only inside this scope
#define CONVCG(CG) { \
        float a0=0,a1=0,a2=0,a3=0,a4=0,a5=0,a6=0,a7=0,a8=0,a9=0,a10=0,a11=0, \
              a12=0,a13=0,a14=0,a15=0,a16=0,a17=0,a18=0,a19=0,a20=0,a21=0,a22=0,a23=0; \
        ALLSTEPS(CG) \
        float m0 = fmaxf(fmaxf(fmaxf(a0,a1),fmaxf(a2,a3)),fmaxf(fmaxf(a4,a5),fmaxf(a6,a7))); \
        float m1 = fmaxf(fmaxf(fmaxf(a8,a9),fmaxf(a10,a11)),fmaxf(fmaxf(a12,a13),fmaxf(a14,a15))); \
        float m2 = fmaxf(fmaxf(fmaxf(a16,a17),fmaxf(a18,a19)),fmaxf(fmaxf(a20,a21),fmaxf(a22,a23))); \
        out[((CG) * 3 + 0) * HWSZ + y * WW + x] = m0; \
        out[((CG) * 3 + 1) * HWSZ + y * WW + x] = m1; \
        out[((CG) * 3 + 2) * HWSZ + y * WW + x] = m2; \
        RED((CG) * 3 + 0, m0) RED((CG) * 3 + 1, m1) RED((CG) * 3 + 2, m2) \
    }

// ---- Kernel 1: fused bank+conv. Each block computes the 1800-float Gabor bank into
// LDS (~7 transcendental iters/thread, hidden under the tile-stage HBM latency), then
// convolves its 16x16 tile for all 9 channels. Per-block sums go to partial[] --
// no atomics, no zero-init dependency. ----
__global__ __launch_bounds__(256) void conv_kernel(
    const float* __restrict__ img,
    const float* __restrict__ sigmas, const float* __restrict__ lambdas,
    float* __restrict__ out, float* __restrict__ partial) {
    __shared__ float tile[20 * 20];
    __shared__ __align__(16) float flds[1800];
    __shared__ float red[4][9];
    int tid = threadIdx.x;
    int tx = tid & 15, ty = tid >> 4;
    int bx = blockIdx.x, by = blockIdx.y;

    // stage image tile (global loads issue first; filter math below overlaps the latency)
    for (int i = tid; i < 400; i += 256) {
        int tY = i / 20, tX = i % 20;
        int gy = by * 16 + tY - 2, gx = bx * 16 + tX - 2;
        float v = 0.0f;
        if (gy >= 0 && gy < HH && gx >= 0 && gx < WW) v = img[gy * WW + gx];
        tile[i] = v;
    }
    // compute Gabor bank into LDS -- bit-identical math to the old bank_kernel
    for (int idx = tid; idx < 1800; idx += 256) {
        int f = idx / 25, k = idx % 25;
        int dy = k / 5, dx = k % 5;
        int s = f / 24, rem = f % 24, l = rem / 8, t = rem % 8;
        float sig = sigmas[s], lam = lambdas[l], th = c_thetas[t];
        float yy = (float)dy - 2.0f, xx = (float)dx - 2.0f;
        float st = sinf(th), ct = cosf(th);
        float yt = -xx * st + yy * ct;
        float xt =  xx * ct + yy * st;
        float sx2 = sig * sig;          // sigma_x = sig
        float sy2 = 4.0f * sig * sig;   // sigma_y = sig/0.5
        float g = expf(-0.5f * (xt * xt / sx2 + yt * yt / sy2)) *
                  cosf(6.28318530717958647692f * xt / lam + 1.5707963267948966f);
        flds[k * 72 + f] = g;           // transposed layout: filt[k][f]
    }
    __syncthreads();

    int tbase = ty * 20 + tx;
    // hoist the 25 pixel loads into named registers (exactly 25 ds_read_b32, shared by all cgs)
    float p0  = tile[tbase +  0], p1  = tile[tbase +  1], p2  = tile[tbase +  2],
          p3  = tile[tbase +  3], p4  = tile[tbase +  4];
    float p5  = tile[tbase + 20], p6  = tile[tbase + 21], p7  = tile[tbase + 22],
          p8  = tile[tbase + 23], p9  = tile[tbase + 24];
    float p10 = tile[tbase + 40], p11 = tile[tbase + 41], p12 = tile[tbase + 42],
          p13 = tile[tbase + 43], p14 = tile[tbase + 44];
    float p15 = tile[tbase + 60], p16 = tile[tbase + 61], p17 = tile[tbase + 62],
          p18 = tile[tbase + 63], p19 = tile[tbase + 64];
    float p20 = tile[tbase + 80], p21 = tile[tbase + 81], p22 = tile[tbase + 82],
          p23 = tile[tbase + 83], p24 = tile[tbase + 84];

    int y = by * 16 + ty, x = bx * 16 + tx;

    CONVCG(0)
    CONVCG(1)
    CONVCG(2)

    __syncthreads();
    if (tid < 9) {
        int bid = by * NW + bx;
        partial[tid * PARTSTRIDE + bid] =
            red[0][tid] + red[1][tid] + red[2][tid] + red[3][tid];
    }
}

// ---- Kernel 2: mean-reduce preamble + per-window validity + patch copy (valid ~3.5%) ----
__global__ __launch_bounds__(256) void patch_kernel(
    const float* __restrict__ out, const float* __restrict__ partial,
    float* __restrict__ dst) {
    int w = blockIdx.x;
    int r = w / NW, cl = w % NW;
    int tid = threadIdx.x;
    __shared__ float sm5[9];
    __shared__ int lds_and[4];
    __shared__ int lds_or[4];

    // Preamble: reduce per-block conv partials -> 5*mean per channel (all L2-hits)
    {
        int lane = tid & 63, wid = tid >> 6;
        for (int c = wid; c < 9; c += 4) {
            float s = 0.0f;
            for (int b = lane; b < NWIN; b += 64) s += partial[c * PARTSTRIDE + b];
            s += __shfl_down(s, 32, 64); s += __shfl_down(s, 16, 64);
            s += __shfl_down(s,  8, 64); s += __shfl_down(s,  4, 64);
            s += __shfl_down(s,  2, 64); s += __shfl_down(s,  1, 64);
            if (lane == 0) sm5[c] = s * (5.0f / (float)HWSZ);
        }
    }
    __syncthreads();

    // Stage 1: per-channel "argmax of thresholded window == 128" bit, AND over threads
    int wy = tid >> 4, wx = tid & 15;
    int rowbase = (r * 16 + wy) * WW + cl * 16 + wx;
    int cbase   = (r * 16 + 8) * WW + cl * 16;       // flat idx 128 = (8,0)
    int okmask = 0;
#pragma unroll
    for (int c = 0; c < 9; c++) {
        float m5 = sm5[c];
        float v  = out[c * HWSZ + rowbase];
        float vc = out[c * HWSZ + cbase];
        float thr  = (v  > m5) ? v  : 0.0f;
        float thrc = (vc > m5) ? vc : 0.0f;
        // first-occurrence argmax: earlier strictly less, later (incl. center) <=
        bool ok = (tid < 128) ? (thr < thrc) : (thr <= thrc);
        okmask |= (ok ? 1 : 0) << c;
    }
#pragma unroll
    for (int off = 1; off < 64; off <<= 1) okmask &= __shfl_xor(okmask, off, 64);
    if ((tid & 63) == 0) lds_and[tid >> 6] = okmask;
    __syncthreads();

    int am = lds_and[0] & lds_and[1] & lds_and[2] & lds_and[3];

    int i = tid >> 3;            // patch row 0..31
    int jg = (tid & 7) << 2;     // patch col group 0,4,...,28
    size_t dbase = (size_t)w * 1024 + i * 32 + jg;

    if (am == 0) {
        // no channel has center-argmax: entire 9-channel patch set is zero.
        // must still store (dst is poisoned), but skip all patch reads.
        nf4 z = (nf4){0.f, 0.f, 0.f, 0.f};
#pragma unroll
        for (int c = 0; c < 9; c++)
            __builtin_nontemporal_store(z, (nf4*)(dst + (size_t)c * NWIN * 1024 + dbase));
        return;
    }

    // Stage 2 (valid windows only): one float4 per (thread, channel); nz bitmask
    int row = r * 16 + i - 8;
    int col = cl * 16 + jg - 8;
    // 4-aligned col groups never straddle the [0,496) edge (496 % 4 == 0)
    bool inb = (row >= 0 && row < HH && col >= 0 && col + 3 < WW);
    size_t pbase = (size_t)row * WW + col;
    int nzmask = 0;
    nf4 p0, p1, p2, p3, p4, p5, p6, p7, p8;
#define LOADP(C, V) { \
        V = (nf4){0.f, 0.f, 0.f, 0.f}; \
        if (inb) V = *(const nf4*)(out + (size_t)(C) * HWSZ + pbase); \
        if (V.x != 0.f || V.y != 0.f || V.z != 0.f || V.w != 0.f) nzmask |= 1 << (C); }
    LOADP(0,p0) LOADP(1,p1) LOADP(2,p2) LOADP(3,p3) LOADP(4,p4)
    LOADP(5,p5) LOADP(6,p6) LOADP(7,p7) LOADP(8,p8)

#pragma unroll
    for (int off = 1; off < 64; off <<= 1) nzmask |= __shfl_xor(nzmask, off, 64);
    if ((tid & 63) == 0) lds_or[tid >> 6] = nzmask;
    __syncthreads();

    int om = lds_or[0] | lds_or[1] | lds_or[2] | lds_or[3];

    // nontemporal: dst is streaming (35.4 MB, never re-read) -- keep `out` in L2
#define STOREP(C, V) { \
        float mk = ((om >> (C)) & 1) ? 1.0f : 0.0f; \
        V *= mk; \
        __builtin_nontemporal_store(V, (nf4*)(dst + (size_t)(C) * NWIN * 1024 + dbase)); }
    STOREP(0,p0) STOREP(1,p1) STOREP(2,p2) STOREP(3,p3) STOREP(4,p4)
    STOREP(5,p5) STOREP(6,p6) STOREP(7,p7) STOREP(8,p8)
}

extern "C" void kernel_launch(void* const* d_in, const int* in_sizes, int n_in,
                              void* d_out, int out_size, void* d_ws, size_t ws_size,
                              hipStream_t stream) {
    const float* img     = (const float*)d_in[0];
    const float* sigmas  = (const float*)d_in[1];
    const float* lambdas = (const float*)d_in[2];
    float* ws = (float*)d_ws;
    // ws layout (floats): partial[9*1024] @0, out @16384
    float* partial = ws;
    float* outb    = ws + 16384;   // 9*496*496 = 2,214,144 floats

    conv_kernel<<<dim3(NW, NW), 256, 0, stream>>>(img, sigmas, lambdas, outb, partial);
    patch_kernel<<<NWIN, 256, 0, stream>>>(outb, partial, (float*)d_out);
}